// Round 8
// baseline (508.192 us; speedup 1.0000x reference)
//
#include <hip/hip_runtime.h>

#define B_ 32
#define C_ 512
#define HW_ 4096
#define N_ 80
#define HSPLIT 2
#define REPS 4  // measurement instrumentation: identical idempotent reps

typedef __bf16 bf16x8 __attribute__((ext_vector_type(8)));
typedef __bf16 bf16x4 __attribute__((ext_vector_type(4)));
typedef float f32x4 __attribute__((ext_vector_type(4)));
typedef unsigned short u16x8 __attribute__((ext_vector_type(8)));

__device__ __forceinline__ void gload_lds16(const void* g, void* l) {
  __builtin_amdgcn_global_load_lds((const __attribute__((address_space(1))) void*)g,
                                   (__attribute__((address_space(3))) void*)l, 16, 0, 0);
}

#define WAIT_VM0_BAR()                                  \
  do {                                                  \
    asm volatile("s_waitcnt vmcnt(0)" ::: "memory");    \
    __builtin_amdgcn_s_barrier();                       \
  } while (0)

// ---------------------------------------------------------------------------
// K0: refragment W -> Wfrag bf16 (as R7)
// ---------------------------------------------------------------------------
__global__ __launch_bounds__(256) void k0_wfrag(const float* __restrict__ W,
                                                __bf16* __restrict__ Wfrag) {
  const int t = blockIdx.x * 256 + threadIdx.x;
  if (t >= 16 * 5 * 64) return;
  const int cs = t / 320, rem = t % 320;
  const int nf = rem >> 6, lane = rem & 63;
  const int n = nf * 16 + (lane & 15);
  const int c = cs * 32 + (lane >> 4) * 8;
  const float* wp = W + (size_t)n * C_ + c;
  bf16x8 v;
#pragma unroll
  for (int i = 0; i < 8; ++i) v[i] = (__bf16)wp[i];
  *(bf16x8*)(Wfrag + (size_t)t * 8) = v;
}

__global__ __launch_bounds__(256) void kz_zero(float* __restrict__ denom) {
  const int i = blockIdx.x * 256 + threadIdx.x;
  if (i < B_ * N_) denom[i] = 0.f;
}

// ---------------------------------------------------------------------------
// K1 (instrumented x REPS): E = exp(feats^T W^T); denom row sums (last rep).
// Structure identical to R7 otherwise.
// ---------------------------------------------------------------------------
__device__ __forceinline__ void k1_stage(const float* fb, float* buf, int cs,
                                         int htile0, int wave, int lane) {
#pragma unroll
  for (int j = 0; j < 8; ++j) {
    const int r = j * 4 + wave;
    const float* gp = fb + (size_t)(cs * 32 + r) * HW_ + htile0 + lane * 4;
    gload_lds16(gp, (char*)buf + r * 1024);
  }
}

__global__ __launch_bounds__(256, 2) void k1_logits(const float* __restrict__ feats,
                                                    const __bf16* __restrict__ Wfrag,
                                                    __bf16* __restrict__ E,
                                                    float* __restrict__ denom) {
  __shared__ float tile[2][32 * 256];  // 2 x 32 KB
  const int tid = threadIdx.x;
  const int lane = tid & 63, wave = tid >> 6;
  const int quad = lane >> 4, l16 = lane & 15;
  const int b = blockIdx.y;
  const int htile0 = blockIdx.x * 256;
  const float* fb = feats + (size_t)b * (C_ * HW_);
  const f32x4 zero = {0.f, 0.f, 0.f, 0.f};

  for (int rep = 0; rep < REPS; ++rep) {
    f32x4 acc[4][5];
#pragma unroll
    for (int hf = 0; hf < 4; ++hf)
#pragma unroll
      for (int nf = 0; nf < 5; ++nf) acc[hf][nf] = zero;

    k1_stage(fb, tile[0], 0, htile0, wave, lane);
    WAIT_VM0_BAR();

    for (int cs = 0; cs < 16; ++cs) {
      const int cur = cs & 1;
      if (cs + 1 < 16) k1_stage(fb, tile[cur ^ 1], cs + 1, htile0, wave, lane);

      const float* tb = tile[cur];
      bf16x8 afr[4];
#pragma unroll
      for (int hf = 0; hf < 4; ++hf) {
        const int col = wave * 64 + hf * 16 + l16;
#pragma unroll
        for (int i = 0; i < 8; ++i) afr[hf][i] = (__bf16)tb[(quad * 8 + i) * 256 + col];
      }
#pragma unroll
      for (int nf = 0; nf < 5; ++nf) {
        const u16x8 bv = *(const u16x8*)(Wfrag + ((size_t)(cs * 5 + nf) * 64 + lane) * 8);
        const bf16x8 bfr = __builtin_bit_cast(bf16x8, bv);
#pragma unroll
        for (int hf = 0; hf < 4; ++hf)
          acc[hf][nf] =
              __builtin_amdgcn_mfma_f32_16x16x32_bf16(afr[hf], bfr, acc[hf][nf], 0, 0, 0);
      }
      WAIT_VM0_BAR();
    }

#pragma unroll
    for (int nf = 0; nf < 5; ++nf) {
      const int n = nf * 16 + l16;
      float s = 0.f;
#pragma unroll
      for (int hf = 0; hf < 4; ++hf) {
        bf16x4 pk;
#pragma unroll
        for (int j = 0; j < 4; ++j) {
          const float e = __expf(acc[hf][nf][j]);
          s += e;
          pk[j] = (__bf16)e;
        }
        const int h = htile0 + wave * 64 + hf * 16 + quad * 4;
        *(bf16x4*)(E + (size_t)(b * N_ + n) * HW_ + h) = pk;
      }
      if (rep == REPS - 1) {
        s += __shfl_xor(s, 16);
        s += __shfl_xor(s, 32);
        if (lane < 16) atomicAdd(denom + b * N_ + nf * 16 + lane, s);
      }
    }
    __syncthreads();  // keep reps aligned across waves
  }
}

// ---------------------------------------------------------------------------
// K3 (instrumented x REPS): part = E * feats^T over h slice. As R7 otherwise.
// ---------------------------------------------------------------------------
__device__ __forceinline__ void k3_stage(const float* fb, const __bf16* eb,
                                         float* bufA, __bf16* bufB, int c0, int h0,
                                         int wave, int lane) {
  const int tid = wave * 64 + lane;
#pragma unroll
  for (int j = 0; j < 4; ++j) {  // fA: 32 rows x 32 units
    const int d = j * 256 + tid;
    const int r = d >> 5, p = d & 31;
    const int ul = p ^ (r & 15);
    const float* gp = fb + (size_t)(c0 + r) * HW_ + h0 + ul * 4;
    gload_lds16(gp, (char*)bufA + j * 4096 + wave * 1024);
  }
#pragma unroll
  for (int j = 0; j < 5; ++j) {  // fB: 80 rows x 16 units
    const int d = j * 256 + tid;
    const int r = d >> 4, p = d & 15;
    const int ul = p ^ (r & 15);
    const __bf16* gp = eb + (size_t)r * HW_ + h0 + ul * 8;
    gload_lds16(gp, (char*)bufB + j * 4096 + wave * 1024);
  }
}

__global__ __launch_bounds__(256, 2) void k3_pool(const float* __restrict__ feats,
                                                  const __bf16* __restrict__ E,
                                                  float* __restrict__ part) {
  __shared__ float fA[2][32 * 128];    // 2 x 16 KB
  __shared__ __bf16 fB[2][80 * 128];   // 2 x 20 KB
  const int tid = threadIdx.x;
  const int lane = tid & 63, w = tid >> 6;
  const int quad = lane >> 4, l16 = lane & 15;
  const int cf = w & 1, ng = w >> 1;
  const int nfbase = ng ? 3 : 0, nfcnt = ng ? 2 : 3;
  const int b = blockIdx.y, hz = blockIdx.z;
  const int c0 = blockIdx.x * 32;
  const float* fb = feats + (size_t)b * (C_ * HW_);
  const __bf16* eb = E + (size_t)b * N_ * HW_;
  const int hbeg = hz * (HW_ / HSPLIT);
  const f32x4 zero = {0.f, 0.f, 0.f, 0.f};
  const int c = cf * 16 + l16;
  const int nt = (HW_ / HSPLIT) / 128;

  for (int rep = 0; rep < REPS; ++rep) {
    f32x4 acc[3];
#pragma unroll
    for (int i = 0; i < 3; ++i) acc[i] = zero;

    k3_stage(fb, eb, fA[0], fB[0], c0, hbeg, w, lane);
    WAIT_VM0_BAR();

    for (int t = 0; t < nt; ++t) {
      const int cur = t & 1;
      if (t + 1 < nt)
        k3_stage(fb, eb, fA[cur ^ 1], fB[cur ^ 1], c0, hbeg + (t + 1) * 128, w, lane);

#pragma unroll
      for (int ks = 0; ks < 4; ++ks) {
        const int u0 = (ks * 8 + quad * 2) ^ l16;
        const int u1 = (ks * 8 + quad * 2 + 1) ^ l16;
        const f32x4 va = *(const f32x4*)&fA[cur][c * 128 + u0 * 4];
        const f32x4 vb = *(const f32x4*)&fA[cur][c * 128 + u1 * 4];
        bf16x8 af;
        af[0] = (__bf16)va[0]; af[1] = (__bf16)va[1];
        af[2] = (__bf16)va[2]; af[3] = (__bf16)va[3];
        af[4] = (__bf16)vb[0]; af[5] = (__bf16)vb[1];
        af[6] = (__bf16)vb[2]; af[7] = (__bf16)vb[3];
#pragma unroll
        for (int nfl = 0; nfl < 3; ++nfl) {
          if (nfl >= nfcnt) break;
          const int n = (nfbase + nfl) * 16 + l16;
          const int ub = (ks * 4 + quad) ^ l16;
          const u16x8 bv = *(const u16x8*)&fB[cur][n * 128 + ub * 8];
          const bf16x8 bfr = __builtin_bit_cast(bf16x8, bv);
          acc[nfl] = __builtin_amdgcn_mfma_f32_16x16x32_bf16(af, bfr, acc[nfl], 0, 0, 0);
        }
      }
      WAIT_VM0_BAR();
    }

    float* pb = part + (size_t)hz * (B_ * N_ * C_);
#pragma unroll
    for (int nfl = 0; nfl < 3; ++nfl) {
      if (nfl >= nfcnt) break;
      const int n = (nfbase + nfl) * 16 + l16;
      float4 v;
      v.x = acc[nfl][0]; v.y = acc[nfl][1]; v.z = acc[nfl][2]; v.w = acc[nfl][3];
      *(float4*)(pb + (size_t)(b * N_ + n) * C_ + c0 + cf * 16 + quad * 4) = v;
    }
    __syncthreads();
  }
}

// ---------------------------------------------------------------------------
// K4: out = (sum_hz part[hz]) / denom[b][n]
// ---------------------------------------------------------------------------
__global__ __launch_bounds__(256) void k4_reduce(const float* __restrict__ part,
                                                 const float* __restrict__ denom,
                                                 float* __restrict__ out) {
  const size_t i = ((size_t)blockIdx.x * 256 + threadIdx.x) * 4;
  if (i >= (size_t)B_ * N_ * C_) return;
  float4 s = *(const float4*)(part + i);
#pragma unroll
  for (int hz = 1; hz < HSPLIT; ++hz) {
    const float4 v = *(const float4*)(part + (size_t)hz * (B_ * N_ * C_) + i);
    s.x += v.x; s.y += v.y; s.z += v.z; s.w += v.w;
  }
  const float r = 1.0f / denom[i >> 9];
  s.x *= r; s.y *= r; s.z *= r; s.w *= r;
  *(float4*)(out + i) = s;
}

extern "C" void kernel_launch(void* const* d_in, const int* in_sizes, int n_in,
                              void* d_out, int out_size, void* d_ws, size_t ws_size,
                              hipStream_t stream) {
  (void)in_sizes; (void)n_in; (void)out_size; (void)ws_size;
  const float* feats = (const float*)d_in[0];
  const float* Wm = (const float*)d_in[1];
  float* out = (float*)d_out;

  __bf16* E = (__bf16*)d_ws;                       // 21 MB
  __bf16* Wfrag = E + (size_t)B_ * N_ * HW_;       // 80 KB
  float* part = (float*)(Wfrag + 16 * 5 * 64 * 8); // HSPLIT x 5.24 MB
  float* denom = part + (size_t)HSPLIT * B_ * N_ * C_;  // 10 KB

  hipLaunchKernelGGL(k0_wfrag, dim3(20), dim3(256), 0, stream, Wm, Wfrag);
  hipLaunchKernelGGL(kz_zero, dim3(10), dim3(256), 0, stream, denom);
  hipLaunchKernelGGL(k1_logits, dim3(HW_ / 256, B_), dim3(256), 0, stream, feats, Wfrag, E, denom);
  hipLaunchKernelGGL(k3_pool, dim3(C_ / 32, B_, HSPLIT), dim3(256), 0, stream, feats, E, part);
  const int n4 = (B_ * N_ * C_) / 4;
  hipLaunchKernelGGL(k4_reduce, dim3(n4 / 256), dim3(256), 0, stream, part, denom, out);
}

// Round 9
// 131.924 us; speedup vs baseline: 3.8522x; 3.8522x over previous
//
#include <hip/hip_runtime.h>

#define B_ 32
#define C_ 512
#define HW_ 4096
#define N_ 80
#define HSPLIT 2

typedef __bf16 bf16x8 __attribute__((ext_vector_type(8)));
typedef __bf16 bf16x4 __attribute__((ext_vector_type(4)));
typedef float f32x4 __attribute__((ext_vector_type(4)));
typedef unsigned short u16x8 __attribute__((ext_vector_type(8)));

__device__ __forceinline__ void gload_lds16(const void* g, void* l) {
  __builtin_amdgcn_global_load_lds((const __attribute__((address_space(1))) void*)g,
                                   (__attribute__((address_space(3))) void*)l, 16, 0, 0);
}

#define VMCNT(n) asm volatile("s_waitcnt vmcnt(" #n ")" ::: "memory")
#define SBAR() asm volatile("s_barrier" ::: "memory")

// ---------------------------------------------------------------------------
// K0: refragment W -> Wfrag bf16: unit t = (cs*5+nf)*64+lane holds
//     W[nf*16+(lane&15)][cs*32+(lane>>4)*8 .. +8]
// ---------------------------------------------------------------------------
__global__ __launch_bounds__(256) void k0_wfrag(const float* __restrict__ W,
                                                __bf16* __restrict__ Wfrag) {
  const int t = blockIdx.x * 256 + threadIdx.x;
  if (t >= 16 * 5 * 64) return;
  const int cs = t / 320, rem = t % 320;
  const int nf = rem >> 6, lane = rem & 63;
  const int n = nf * 16 + (lane & 15);
  const int c = cs * 32 + (lane >> 4) * 8;
  const float* wp = W + (size_t)n * C_ + c;
  bf16x8 v;
#pragma unroll
  for (int i = 0; i < 8; ++i) v[i] = (__bf16)wp[i];
  *(bf16x8*)(Wfrag + (size_t)t * 8) = v;
}

__global__ __launch_bounds__(256) void kz_zero(float* __restrict__ denom) {
  const int i = blockIdx.x * 256 + threadIdx.x;
  if (i < B_ * N_) denom[i] = 0.f;
}

// ---------------------------------------------------------------------------
// K1: E[b][n][h] = exp(sum_c feats[b][c][h] * W[n][c]); denom += row sums.
// Counted-vmcnt pipeline: 3 tile buffers [32c][128h] f32 (16 KB), depth-2
// stage prefetch + 1-ahead Wfrag register prefetch (named sets, rule #20).
// Iter = [vmcnt(9); s_barrier; load wf(t+1); stage(t+2); compute(t)].
// FIFO accounting: newer-than-stage(t) = wf(t):5 + stage(t+1):4 = 9.
// Grid (HW/128, B) = 1024 blocks, 4 waves, 3 blocks/CU (48 KB LDS).
// ---------------------------------------------------------------------------
#define K1_STAGE(CS, SLOT)                                                      \
  {                                                                             \
    _Pragma("unroll") for (int j = 0; j < 4; ++j) {                             \
      const int d = j * 256 + tid;                                              \
      const int r = d >> 5, p = d & 31;                                         \
      gload_lds16(fb + (size_t)((CS)*32 + r) * HW_ + htile0 + p * 4,            \
                  (char*)tile + (SLOT)*16384 + (j * 256 + wave * 64) * 16);     \
    }                                                                           \
  }

#define K1_WLOAD(W, CS)                                                         \
  {                                                                             \
    _Pragma("unroll") for (int nf = 0; nf < 5; ++nf)                            \
        W[nf] = *(const u16x8*)(Wfrag + ((size_t)((CS)*5 + nf) * 64 + lane) * 8); \
  }

#define K1_COMPUTE(T, WU)                                                       \
  {                                                                             \
    const float* tb = (const float*)((char*)tile + ((T) % 3) * 16384);          \
    bf16x8 afr[2];                                                              \
    _Pragma("unroll") for (int hf = 0; hf < 2; ++hf) {                          \
      const int col = wave * 32 + hf * 16 + l16;                                \
      _Pragma("unroll") for (int i = 0; i < 8; ++i)                             \
          afr[hf][i] = (__bf16)tb[(quad * 8 + i) * 128 + col];                  \
    }                                                                           \
    _Pragma("unroll") for (int nf = 0; nf < 5; ++nf) {                          \
      const bf16x8 bfr = __builtin_bit_cast(bf16x8, WU[nf]);                    \
      acc[0][nf] = __builtin_amdgcn_mfma_f32_16x16x32_bf16(afr[0], bfr, acc[0][nf], 0, 0, 0); \
      acc[1][nf] = __builtin_amdgcn_mfma_f32_16x16x32_bf16(afr[1], bfr, acc[1][nf], 0, 0, 0); \
    }                                                                           \
  }

#define K1_ITER(T, WU, WL)                                                      \
  {                                                                             \
    VMCNT(9); SBAR();                                                           \
    K1_WLOAD(WL, (T) + 1);                                                      \
    if ((T) + 2 < 16) K1_STAGE((T) + 2, ((T) + 2) % 3);                         \
    K1_COMPUTE(T, WU);                                                          \
  }

__global__ __launch_bounds__(256, 3) void k1_logits(const float* __restrict__ feats,
                                                    const __bf16* __restrict__ Wfrag,
                                                    __bf16* __restrict__ E,
                                                    float* __restrict__ denom) {
  __shared__ float tile[3][32 * 128];  // 48 KB
  const int tid = threadIdx.x;
  const int lane = tid & 63, wave = tid >> 6;
  const int quad = lane >> 4, l16 = lane & 15;
  const int b = blockIdx.y;
  const int htile0 = blockIdx.x * 128;
  const float* fb = feats + (size_t)b * (C_ * HW_);

  const f32x4 zero = {0.f, 0.f, 0.f, 0.f};
  f32x4 acc[2][5];
#pragma unroll
  for (int hf = 0; hf < 2; ++hf)
#pragma unroll
    for (int nf = 0; nf < 5; ++nf) acc[hf][nf] = zero;

  u16x8 wfA[5], wfB[5];
  // prologue (order fixes FIFO accounting): s0, wf0, s1
  K1_STAGE(0, 0);
  K1_WLOAD(wfA, 0);
  K1_STAGE(1, 1);

  for (int t = 0; t < 14; t += 2) {
    K1_ITER(t, wfA, wfB);
    K1_ITER(t + 1, wfB, wfA);
  }
  K1_ITER(14, wfA, wfB);   // loads wf15 -> wfB; no stage(16)
  VMCNT(5); SBAR();
  K1_COMPUTE(15, wfB);

  // Epilogue: exp, bf16 E store, per-row denom atomics.
#pragma unroll
  for (int nf = 0; nf < 5; ++nf) {
    const int n = nf * 16 + l16;
    float s = 0.f;
#pragma unroll
    for (int hf = 0; hf < 2; ++hf) {
      bf16x4 pk;
#pragma unroll
      for (int j = 0; j < 4; ++j) {
        const float e = __expf(acc[hf][nf][j]);
        s += e;
        pk[j] = (__bf16)e;
      }
      const int h = htile0 + wave * 32 + hf * 16 + quad * 4;
      *(bf16x4*)(E + (size_t)(b * N_ + n) * HW_ + h) = pk;
    }
    s += __shfl_xor(s, 16);
    s += __shfl_xor(s, 32);
    if (lane < 16) atomicAdd(denom + b * N_ + nf * 16 + lane, s);
  }
}

// ---------------------------------------------------------------------------
// K3: part[hz][b][n][c] = sum_{h slice} E[b][n][h] * feats[b][c][h]
// Counted-vmcnt pipeline: 4 buffers of {fA [32c][64h] f32 8KB, fB [80n][64h]
// bf16 10KB}, depth-3, 5 uniform gload_lds/thread per stage (fB row 64..79
// round duplicated across wave pairs to keep per-wave counts uniform).
// XOR source-swizzle: fA phys p holds logical p^(r&15); fB p^(r&7).
// Iter = [vmcnt(10); s_barrier; stage(t+3); compute(t)]; tails 10/5/0.
// XCD-chunked remap: 16 c-blocks sharing an E slice land on one XCD L2.
// Grid 1024 flat, 4 waves, 2 blocks/CU (72 KB LDS).
// ---------------------------------------------------------------------------
#define K3_STAGE(TK, SLOT)                                                      \
  {                                                                             \
    const int h0 = hbeg + (TK)*64;                                              \
    _Pragma("unroll") for (int j = 0; j < 2; ++j) {                             \
      const int d = j * 256 + tid;                                              \
      const int r = d >> 4, p = d & 15;                                         \
      gload_lds16(fb + (size_t)(c0 + r) * HW_ + h0 + ((p ^ (r & 15)) << 2),     \
                  (char*)fA + (SLOT)*8192 + (j * 256 + wave * 64) * 16);        \
    }                                                                           \
    _Pragma("unroll") for (int j = 0; j < 2; ++j) {                             \
      const int d = j * 256 + tid;                                              \
      const int r = d >> 3, p = d & 7;                                          \
      gload_lds16(eb + (size_t)r * HW_ + h0 + ((p ^ (r & 7)) << 3),             \
                  (char*)fB + (SLOT)*10240 + (j * 256 + wave * 64) * 16);       \
    }                                                                           \
    {                                                                           \
      const int d = 512 + (wave & 1) * 64 + lane;                               \
      const int r = d >> 3, p = d & 7;                                          \
      gload_lds16(eb + (size_t)r * HW_ + h0 + ((p ^ (r & 7)) << 3),             \
                  (char*)fB + (SLOT)*10240 + (512 + (wave & 1) * 64) * 16);     \
    }                                                                           \
  }

#define K3_COMPUTE(T)                                                           \
  {                                                                             \
    const float* A = (const float*)((char*)fA + ((T) % 4) * 8192);              \
    const __bf16* Bv = (const __bf16*)((char*)fB + ((T) % 4) * 10240);          \
    _Pragma("unroll") for (int ks = 0; ks < 2; ++ks) {                          \
      const int u0 = (ks * 8 + quad * 2) ^ l16;                                 \
      const int u1 = (ks * 8 + quad * 2 + 1) ^ l16;                             \
      const f32x4 va = *(const f32x4*)&A[rA * 64 + u0 * 4];                     \
      const f32x4 vb = *(const f32x4*)&A[rA * 64 + u1 * 4];                     \
      bf16x8 af;                                                                \
      af[0] = (__bf16)va[0]; af[1] = (__bf16)va[1];                             \
      af[2] = (__bf16)va[2]; af[3] = (__bf16)va[3];                             \
      af[4] = (__bf16)vb[0]; af[5] = (__bf16)vb[1];                             \
      af[6] = (__bf16)vb[2]; af[7] = (__bf16)vb[3];                             \
      _Pragma("unroll") for (int nfl = 0; nfl < 3; ++nfl) {                     \
        if (nfl >= nfcnt) break;                                                \
        const int n = (nfbase + nfl) * 16 + l16;                                \
        const int ub = (ks * 4 + quad) ^ (l16 & 7);                             \
        const u16x8 bv = *(const u16x8*)&Bv[n * 64 + ub * 8];                   \
        const bf16x8 bfr = __builtin_bit_cast(bf16x8, bv);                      \
        acc[nfl] = __builtin_amdgcn_mfma_f32_16x16x32_bf16(af, bfr, acc[nfl], 0, 0, 0); \
      }                                                                         \
    }                                                                           \
  }

__global__ __launch_bounds__(256, 2) void k3_pool(const float* __restrict__ feats,
                                                  const __bf16* __restrict__ E,
                                                  float* __restrict__ part) {
  __shared__ float fA[4][32 * 64];    // 32 KB
  __shared__ __bf16 fB[4][80 * 64];   // 40 KB
  const int tid = threadIdx.x;
  const int lane = tid & 63, wave = tid >> 6;
  const int quad = lane >> 4, l16 = lane & 15;
  const int cf = wave & 1, ng = wave >> 1;
  const int nfbase = ng ? 3 : 0, nfcnt = ng ? 2 : 3;

  // XCD-chunked remap (bijective: 1024 = 8 * 128)
  const int wg = blockIdx.x;
  const int nid = (wg & 7) * 128 + (wg >> 3);
  const int hz = nid >> 9, rem = nid & 511, b = rem >> 4, cx = rem & 15;
  const int c0 = cx * 32;
  const int hbeg = hz * (HW_ / HSPLIT);

  const float* fb = feats + (size_t)b * (C_ * HW_);
  const __bf16* eb = E + (size_t)b * N_ * HW_;
  const int rA = cf * 16 + l16;

  const f32x4 zero = {0.f, 0.f, 0.f, 0.f};
  f32x4 acc[3];
#pragma unroll
  for (int i = 0; i < 3; ++i) acc[i] = zero;

  K3_STAGE(0, 0);
  K3_STAGE(1, 1);
  K3_STAGE(2, 2);

  for (int t = 0; t < 29; ++t) {
    VMCNT(10); SBAR();
    K3_STAGE(t + 3, (t + 3) & 3);
    K3_COMPUTE(t);
  }
  VMCNT(10); SBAR(); K3_COMPUTE(29);
  VMCNT(5);  SBAR(); K3_COMPUTE(30);
  VMCNT(0);  SBAR(); K3_COMPUTE(31);

  float* pb = part + (size_t)hz * (B_ * N_ * C_);
#pragma unroll
  for (int nfl = 0; nfl < 3; ++nfl) {
    if (nfl >= nfcnt) break;
    const int n = (nfbase + nfl) * 16 + l16;
    float4 v;
    v.x = acc[nfl][0]; v.y = acc[nfl][1]; v.z = acc[nfl][2]; v.w = acc[nfl][3];
    *(float4*)(pb + (size_t)(b * N_ + n) * C_ + c0 + cf * 16 + quad * 4) = v;
  }
}

// ---------------------------------------------------------------------------
// K4: out = (sum_hz part[hz]) / denom[b][n]
// ---------------------------------------------------------------------------
__global__ __launch_bounds__(256) void k4_reduce(const float* __restrict__ part,
                                                 const float* __restrict__ denom,
                                                 float* __restrict__ out) {
  const size_t i = ((size_t)blockIdx.x * 256 + threadIdx.x) * 4;
  if (i >= (size_t)B_ * N_ * C_) return;
  float4 s = *(const float4*)(part + i);
#pragma unroll
  for (int hz = 1; hz < HSPLIT; ++hz) {
    const float4 v = *(const float4*)(part + (size_t)hz * (B_ * N_ * C_) + i);
    s.x += v.x; s.y += v.y; s.z += v.z; s.w += v.w;
  }
  const float r = 1.0f / denom[i >> 9];
  s.x *= r; s.y *= r; s.z *= r; s.w *= r;
  *(float4*)(out + i) = s;
}

extern "C" void kernel_launch(void* const* d_in, const int* in_sizes, int n_in,
                              void* d_out, int out_size, void* d_ws, size_t ws_size,
                              hipStream_t stream) {
  (void)in_sizes; (void)n_in; (void)out_size; (void)ws_size;
  const float* feats = (const float*)d_in[0];
  const float* Wm = (const float*)d_in[1];
  float* out = (float*)d_out;

  __bf16* E = (__bf16*)d_ws;                        // 21 MB
  __bf16* Wfrag = E + (size_t)B_ * N_ * HW_;        // 80 KB
  float* part = (float*)(Wfrag + 16 * 5 * 64 * 8);  // HSPLIT x 5.24 MB
  float* denom = part + (size_t)HSPLIT * B_ * N_ * C_;  // 10 KB

  hipLaunchKernelGGL(k0_wfrag, dim3(20), dim3(256), 0, stream, Wm, Wfrag);
  hipLaunchKernelGGL(kz_zero, dim3(10), dim3(256), 0, stream, denom);
  hipLaunchKernelGGL(k1_logits, dim3(HW_ / 128, B_), dim3(256), 0, stream, feats, Wfrag, E, denom);
  hipLaunchKernelGGL(k3_pool, dim3(1024), dim3(256), 0, stream, feats, E, part);
  const int n4 = (B_ * N_ * C_) / 4;
  hipLaunchKernelGGL(k4_reduce, dim3(n4 / 256), dim3(256), 0, stream, part, denom, out);
}